// Round 11
// baseline (11553.117 us; speedup 1.0000x reference)
//
#include <hip/hip_runtime.h>

#define NS 1024
#define NH 64
#define NB 16384

typedef float f32x2 __attribute__((ext_vector_type(2)));
typedef float f32x4 __attribute__((ext_vector_type(4)));

// Disable FP contraction file-wide: vector a*b+c must stay mul+add (XLA-CPU
// has no contraction). Explicit inline-asm pk_fma used where fma is intended.
#pragma clang fp contract(off)

// v_pk_fma_f32 with src1 broadcast from one register of its 64-bit pair.
// PKFMA_LO: both halves use w.lo ; PKFMA_HI: both halves use w.hi.
// (Semantics HW-verified: R7-R10 passed with absmax 0.0.)
#define PKFMA_LO(acc, h, w)                                                  \
  asm("v_pk_fma_f32 %0, %1, %2, %0 op_sel:[0,0,0] op_sel_hi:[1,0,1]"         \
      : "+v"(acc) : "v"(h), "v"(w))
#define PKFMA_HI(acc, h, w)                                                  \
  asm("v_pk_fma_f32 %0, %1, %2, %0 op_sel:[0,1,0] op_sel_hi:[1,1,1]"         \
      : "+v"(acc) : "v"(h), "v"(w))

// ---- XLA-CPU fp32 op clones, packed over (rowA,rowB); per-component ops
// identical to the verified scalar clone (mul/add unfused, IEEE div). ----

__device__ __forceinline__ f32x2 xexp2v(f32x2 x) {
  x = __builtin_elementwise_min(x, f32x2{88.3762626647950f, 88.3762626647950f});
  x = __builtin_elementwise_max(x, f32x2{-88.3762626647949f, -88.3762626647949f});
  f32x2 fx = __builtin_elementwise_floor(x * 1.44269504088896341f + 0.5f);
  x = x - fx * 0.693359375f;
  x = x - fx * (-2.12194440e-4f);
  f32x2 z = x * x;
  f32x2 y = {1.9875691500e-4f, 1.9875691500e-4f};
  y = y * x + 1.3981999507e-3f;
  y = y * x + 8.3334519073e-3f;
  y = y * x + 4.1665795894e-2f;
  y = y * x + 1.6666665459e-1f;
  y = y * x + 5.0000001201e-1f;
  y = y * z + x;
  y = y + 1.0f;
  int n0 = (int)fx.x, n1 = (int)fx.y;
  float p0 = __int_as_float((n0 + 127) << 23);
  float p1 = __int_as_float((n1 + 127) << 23);
  f32x2 r;
  r.x = __fmul_rn(y.x, p0);
  r.y = __fmul_rn(y.y, p1);
  return r;
}

__device__ __forceinline__ f32x2 xsigmoid2(f32x2 x) {
  f32x2 e = xexp2v(-x);
  f32x2 d = e + 1.0f;
  f32x2 r;
  r.x = __fdiv_rn(1.0f, d.x);
  r.y = __fdiv_rn(1.0f, d.y);
  return r;
}

__device__ __forceinline__ f32x2 xtanh2(f32x2 x) {
  f32x2 xc = __builtin_elementwise_min(
      __builtin_elementwise_max(x, f32x2{-7.90531110763549805f, -7.90531110763549805f}),
      f32x2{7.90531110763549805f, 7.90531110763549805f});
  f32x2 s = xc * xc;
  f32x2 p = {-2.76076847742355e-16f, -2.76076847742355e-16f};
  p = p * s + 2.00018790482477e-13f;
  p = p * s + (-8.60467152213735e-11f);
  p = p * s + 5.12229709037114e-08f;
  p = p * s + 1.48572235717979e-05f;
  p = p * s + 6.37261928875436e-04f;
  p = p * s + 4.89352455891786e-03f;
  f32x2 num = xc * p;
  f32x2 q = {1.19825839466702e-06f, 1.19825839466702e-06f};
  q = q * s + 1.18534705686654e-04f;
  q = q * s + 2.26843463243900e-03f;
  q = q * s + 4.89352518554385e-03f;
  f32x2 rat;
  rat.x = __fdiv_rn(num.x, q.x);
  rat.y = __fdiv_rn(num.y, q.y);
  f32x2 r;
  r.x = (fabsf(x.x) < 0.0004f) ? x.x : rat.x;
  r.y = (fabsf(x.y) < 0.0004f) ? x.y : rat.y;
  return r;
}

__device__ __forceinline__ float rdlane(float v, int l) {
  return __int_as_float(__builtin_amdgcn_readlane(__float_as_int(v), l));
}

// 4 waves/block, TWO rows per wave via packed FP32 (v_pk_fma_f32): lane j
// owns hidden unit j for rows A,B.
//
// R8-R10 lesson: any gate kept in "registers" (64 floats) gets demoted to
// AGPRs by the RA regardless of launch_bounds/sched_barrier -> ~530 issue
// slots/step of accvgpr+mov tax. Fix: ALL THREE gates live in LDS as
// f32x2 pairs (w[kk][j] = (w[2kk],w[2kk+1]), separate array per gate).
// Every ds_read_b64 lands in an even-aligned VGPR pair directly usable as
// the pk_fma broadcast operand - no extraction movs, ~70 live regs, no
// AGPR. LDS 50KB/block -> 3 blocks/CU = 12 waves/CU; DS stays under VALU.
__global__ __launch_bounds__(256, 2) void gru_sample_kernel(
    const float* __restrict__ u, const float* __restrict__ w_ih,
    const float* __restrict__ w_hh, const float* __restrict__ b_ih,
    const float* __restrict__ b_hh, const float* __restrict__ head_w,
    const float* __restrict__ head_b, int* __restrict__ out) {
  const int lane = threadIdx.x & 63;
  const int wv = threadIdx.x >> 6;  // 0..3
  const int rowA = blockIdx.x * 8 + wv * 2;
  const int rowB = rowA + 1;

  __shared__ f32x2 wr_l[32][NH];  // [kk][j] = (w_r[j][2kk], w_r[j][2kk+1])
  __shared__ f32x2 wz_l[32][NH];
  __shared__ f32x2 wn_l[32][NH];
  __shared__ f32x2 hp[4][NH];     // [wave][k] = (hA[k], hB[k])

  // Cooperative weight fill (one-time): 2048 (kk,j) cells over 256 threads.
  for (int idx = threadIdx.x; idx < 32 * NH; idx += 256) {
    int kk = idx & 31, j = idx >> 5;
    wr_l[kk][j] = *(const f32x2*)&w_hh[(size_t)j * NH + 2 * kk];
    wz_l[kk][j] = *(const f32x2*)&w_hh[(size_t)(64 + j) * NH + 2 * kk];
    wn_l[kk][j] = *(const f32x2*)&w_hh[(size_t)(128 + j) * NH + 2 * kk];
  }

  const float bih_r = b_ih[lane], bih_z = b_ih[64 + lane], bih_n = b_ih[128 + lane];
  const float bhh_r = b_hh[lane], bhh_z = b_hh[64 + lane], bhh_n = b_hh[128 + lane];
  // prev ∈ {0,1}: gx = prev*w_ih + b_ih == (prev ? w_ih+b_ih : b_ih) bit-exactly.
  const float sum_r = __fadd_rn(w_ih[lane], bih_r);
  const float sum_z = __fadd_rn(w_ih[64 + lane], bih_z);
  const float sum_n = __fadd_rn(w_ih[128 + lane], bih_n);
  const float hwv = head_w[lane];
  const f32x2 hw2 = {hwv, hwv};
  const float hb = head_b[0];
  __syncthreads();  // weights ready; waves independent afterwards

  const float* urA = u + (size_t)rowA * NS;
  const float* urB = u + (size_t)rowB * NS;
  int* orA = out + (size_t)rowA * NS;
  int* orB = out + (size_t)rowB * NS;

  f32x2 h2 = {0.0f, 0.0f};
  int prevA = 0, prevB = 0;
  hp[wv][lane] = h2;
  const f32x4* hp4 = (const f32x4*)&hp[wv][0];

  for (int c = 0; c < 16; ++c) {
    float uA = urA[c * 64 + lane];
    float uB = urB[c * 64 + lane];
    int mybitA = 0, mybitB = 0;
    for (int tt = 0; tt < 64; ++tt) {
      // gh = h @ w_hh.T for both rows, packed: per-component sequential-k
      // FMA chain from 0 (Eigen gebp clone, components independent).
      f32x2 ar2 = {0.0f, 0.0f}, az2 = {0.0f, 0.0f}, an2 = {0.0f, 0.0f};
#pragma unroll
      for (int kk = 0; kk < 32; ++kk) {
        f32x4 h4 = hp4[kk];            // uniform b128: (hA,hB)@2kk, (hA,hB)@2kk+1
        f32x2 h2a = __builtin_shufflevector(h4, h4, 0, 1);
        f32x2 h2b = __builtin_shufflevector(h4, h4, 2, 3);
        f32x2 wrp = wr_l[kk][lane];    // ds_read_b64 -> aligned pair
        f32x2 wzp = wz_l[kk][lane];
        f32x2 wnp = wn_l[kk][lane];
        PKFMA_LO(ar2, h2a, wrp);       // += h[2kk]   * wr[2kk]
        PKFMA_HI(ar2, h2b, wrp);       // += h[2kk+1] * wr[2kk+1]
        PKFMA_LO(az2, h2a, wzp);
        PKFMA_HI(az2, h2b, wzp);
        PKFMA_LO(an2, h2a, wnp);
        PKFMA_HI(an2, h2b, wnp);
      }
      // gates, exact reference association (packed mul/add are unfused)
      f32x2 ghr2 = ar2 + bhh_r;
      f32x2 ghz2 = az2 + bhh_z;
      f32x2 ghn2 = an2 + bhh_n;
      f32x2 gxr2 = {prevA ? sum_r : bih_r, prevB ? sum_r : bih_r};
      f32x2 gxz2 = {prevA ? sum_z : bih_z, prevB ? sum_z : bih_z};
      f32x2 gxn2 = {prevA ? sum_n : bih_n, prevB ? sum_n : bih_n};
      f32x2 r2 = xsigmoid2(gxr2 + ghr2);
      f32x2 z2 = xsigmoid2(gxz2 + ghz2);
      f32x2 n2 = xtanh2(gxn2 + r2 * ghn2);
      f32x2 omz = 1.0f - z2;           // (1-z): subrev, exact
      h2 = omz * n2 + z2 * h2;         // two muls + add, unfused = clone
      hp[wv][lane] = h2;               // for next step's matvec

      // head gemv clone: width-16 chunks then halving tree (per component)
      f32x2 P2 = h2 * hw2;
      f32x2 t, s2;
      t.x = __shfl(P2.x, lane + 16); t.y = __shfl(P2.y, lane + 16);
      s2 = P2 + t;
      t.x = __shfl(P2.x, lane + 32); t.y = __shfl(P2.y, lane + 32);
      s2 = s2 + t;
      t.x = __shfl(P2.x, lane + 48); t.y = __shfl(P2.y, lane + 48);
      s2 = s2 + t;
      t.x = __shfl(s2.x, lane + 8); t.y = __shfl(s2.y, lane + 8);
      s2 = s2 + t;
      t.x = __shfl(s2.x, lane + 4); t.y = __shfl(s2.y, lane + 4);
      s2 = s2 + t;
      t.x = __shfl(s2.x, lane + 2); t.y = __shfl(s2.y, lane + 2);
      s2 = s2 + t;
      t.x = __shfl(s2.x, lane + 1); t.y = __shfl(s2.y, lane + 1);
      s2 = s2 + t;
      float logitA = __fadd_rn(rdlane(s2.x, 0), hb);
      float logitB = __fadd_rn(rdlane(s2.y, 0), hb);
      f32x2 p2 = xsigmoid2(f32x2{logitA, logitB});

      float uAt = rdlane(uA, tt);
      float uBt = rdlane(uB, tt);
      int bA = (uAt < p2.x) ? 1 : 0;
      int bB = (uBt < p2.y) ? 1 : 0;
      prevA = bA;
      prevB = bB;
      mybitA = (lane == tt) ? bA : mybitA;
      mybitB = (lane == tt) ? bB : mybitB;
    }
    orA[c * 64 + lane] = mybitA;
    orB[c * 64 + lane] = mybitB;
  }
}

extern "C" void kernel_launch(void* const* d_in, const int* in_sizes, int n_in,
                              void* d_out, int out_size, void* d_ws, size_t ws_size,
                              hipStream_t stream) {
  const float* u = (const float*)d_in[0];
  const float* w_ih = (const float*)d_in[1];
  const float* w_hh = (const float*)d_in[2];
  const float* b_ih = (const float*)d_in[3];
  const float* b_hh = (const float*)d_in[4];
  const float* head_w = (const float*)d_in[5];
  const float* head_b = (const float*)d_in[6];
  int* out = (int*)d_out;
  dim3 grid(NB / 8), block(256);
  gru_sample_kernel<<<grid, block, 0, stream>>>(u, w_ih, w_hh, b_ih, b_hh,
                                                head_w, head_b, out);
}

// Round 13
// 9266.592 us; speedup vs baseline: 1.2467x; 1.2467x over previous
//
#include <hip/hip_runtime.h>

#define NS 1024
#define NH 64
#define NB 16384

typedef float f32x2 __attribute__((ext_vector_type(2)));
typedef float f32x4 __attribute__((ext_vector_type(4)));

// Disable FP contraction file-wide: vector a*b+c must stay mul+add (XLA-CPU
// has no contraction). Explicit inline-asm pk_fma used where fma is intended.
#pragma clang fp contract(off)

// v_pk_fma_f32 with src1 broadcast from one register of its 64-bit pair.
// PKFMA_LO: both halves use w.lo ; PKFMA_HI: both halves use w.hi.
// (Semantics HW-verified: R7-R11 passed with absmax 0.0.)
#define PKFMA_LO(acc, h, w)                                                  \
  asm("v_pk_fma_f32 %0, %1, %2, %0 op_sel:[0,0,0] op_sel_hi:[1,0,1]"         \
      : "+v"(acc) : "v"(h), "v"(w))
#define PKFMA_HI(acc, h, w)                                                  \
  asm("v_pk_fma_f32 %0, %1, %2, %0 op_sel:[0,1,0] op_sel_hi:[1,1,1]"         \
      : "+v"(acc) : "v"(h), "v"(w))

// ---- XLA-CPU fp32 op clones, packed over (rowA,rowB); per-component ops
// identical to the verified scalar clone (mul/add unfused, IEEE div). ----

__device__ __forceinline__ f32x2 xexp2v(f32x2 x) {
  x = __builtin_elementwise_min(x, f32x2{88.3762626647950f, 88.3762626647950f});
  x = __builtin_elementwise_max(x, f32x2{-88.3762626647949f, -88.3762626647949f});
  f32x2 fx = __builtin_elementwise_floor(x * 1.44269504088896341f + 0.5f);
  x = x - fx * 0.693359375f;
  x = x - fx * (-2.12194440e-4f);
  f32x2 z = x * x;
  f32x2 y = {1.9875691500e-4f, 1.9875691500e-4f};
  y = y * x + 1.3981999507e-3f;
  y = y * x + 8.3334519073e-3f;
  y = y * x + 4.1665795894e-2f;
  y = y * x + 1.6666665459e-1f;
  y = y * x + 5.0000001201e-1f;
  y = y * z + x;
  y = y + 1.0f;
  int n0 = (int)fx.x, n1 = (int)fx.y;
  float p0 = __int_as_float((n0 + 127) << 23);
  float p1 = __int_as_float((n1 + 127) << 23);
  f32x2 r;
  r.x = __fmul_rn(y.x, p0);
  r.y = __fmul_rn(y.y, p1);
  return r;
}

__device__ __forceinline__ f32x2 xsigmoid2(f32x2 x) {
  f32x2 e = xexp2v(-x);
  f32x2 d = e + 1.0f;
  f32x2 r;
  r.x = __fdiv_rn(1.0f, d.x);
  r.y = __fdiv_rn(1.0f, d.y);
  return r;
}

__device__ __forceinline__ f32x2 xtanh2(f32x2 x) {
  f32x2 xc = __builtin_elementwise_min(
      __builtin_elementwise_max(x, f32x2{-7.90531110763549805f, -7.90531110763549805f}),
      f32x2{7.90531110763549805f, 7.90531110763549805f});
  f32x2 s = xc * xc;
  f32x2 p = {-2.76076847742355e-16f, -2.76076847742355e-16f};
  p = p * s + 2.00018790482477e-13f;
  p = p * s + (-8.60467152213735e-11f);
  p = p * s + 5.12229709037114e-08f;
  p = p * s + 1.48572235717979e-05f;
  p = p * s + 6.37261928875436e-04f;
  p = p * s + 4.89352455891786e-03f;
  f32x2 num = xc * p;
  f32x2 q = {1.19825839466702e-06f, 1.19825839466702e-06f};
  q = q * s + 1.18534705686654e-04f;
  q = q * s + 2.26843463243900e-03f;
  q = q * s + 4.89352518554385e-03f;
  f32x2 rat;
  rat.x = __fdiv_rn(num.x, q.x);
  rat.y = __fdiv_rn(num.y, q.y);
  f32x2 r;
  r.x = (fabsf(x.x) < 0.0004f) ? x.x : rat.x;
  r.y = (fabsf(x.y) < 0.0004f) ? x.y : rat.y;
  return r;
}

__device__ __forceinline__ float rdlane(float v, int l) {
  return __int_as_float(__builtin_amdgcn_readlane(__float_as_int(v), l));
}

// s += s(lane+N) within the 16-lane DPP row, via VALU (not the DS pipe).
// row_shl:N (0x100+N): lane i reads lane i+N (canonical GCN cross-lane
// semantics: row_shr accumulates upward with total in lane 15, row_shl
// downward with total in lane 0 -- R12 used row_shr, which left lane 0
// with only its own partial; that was the absmax=1.0 bug).
// bound_ctrl=true zero-fills lanes reading out-of-row; every source feeding
// lane 0's final value is within lanes 0-15, so lane 0 is bit-exact vs the
// __shfl(s, lane+N) tree.
__device__ __forceinline__ float dpp_shl_add(float s, const int ctrl) {
  int t;
  switch (ctrl) {  // ctrl must be a literal for the builtin
    case 0x108: t = __builtin_amdgcn_update_dpp(0, __float_as_int(s), 0x108, 0xF, 0xF, true); break;
    case 0x104: t = __builtin_amdgcn_update_dpp(0, __float_as_int(s), 0x104, 0xF, 0xF, true); break;
    case 0x102: t = __builtin_amdgcn_update_dpp(0, __float_as_int(s), 0x102, 0xF, 0xF, true); break;
    default:    t = __builtin_amdgcn_update_dpp(0, __float_as_int(s), 0x101, 0xF, 0xF, true); break;
  }
  return __fadd_rn(s, __int_as_float(t));
}

// 4 waves/block, FOUR packed row-pairs (8 rows) per wave. Lane j owns
// hidden unit j for all 8 rows. The DS-pipe is the measured wall (R10/R11):
// per-CU LDS throughput saturates while VALU idles. 8 rows/wave amortizes
// the 32 wzn b128 weight reads (row-count-independent) across 4x the rows,
// and the head-tree tail runs on DPP (VALU) instead of ds_bpermute.
// DS/row-step: 39.5 (R10) -> 23.5. Weights: wr2 in registers (demotion tax,
// if any, hides under DS); wz,wn interleaved in LDS (R10-proven layout).
__global__ __launch_bounds__(256, 2) void gru_sample_kernel(
    const float* __restrict__ u, const float* __restrict__ w_ih,
    const float* __restrict__ w_hh, const float* __restrict__ b_ih,
    const float* __restrict__ b_hh, const float* __restrict__ head_w,
    const float* __restrict__ head_b, int* __restrict__ out) {
  const int lane = threadIdx.x & 63;
  const int wv = threadIdx.x >> 6;  // 0..3
  const int rowBase = blockIdx.x * 32 + wv * 8;

  __shared__ f32x4 wzn[32][NH];    // [kk][j] = (wz[2kk], wn[2kk], wz[2kk+1], wn[2kk+1])
  __shared__ f32x2 hp[4][4][NH];   // [wave][pair][k] = (hA[k], hB[k])

  // Cooperative weight fill (one-time).
  for (int idx = threadIdx.x; idx < 32 * NH; idx += 256) {
    int kk = idx & 31, j = idx >> 5;
    const float* wzrow = w_hh + (size_t)(64 + j) * NH;
    const float* wnrow = w_hh + (size_t)(128 + j) * NH;
    wzn[kk][j] = f32x4{wzrow[2 * kk], wnrow[2 * kk], wzrow[2 * kk + 1], wnrow[2 * kk + 1]};
  }
  // r-gate weights in registers as pairs (wr[2i], wr[2i+1]).
  f32x2 wr2[32];
#pragma unroll
  for (int i = 0; i < 32; ++i)
    wr2[i] = *(const f32x2*)&w_hh[(size_t)lane * NH + 2 * i];

  const float bih_r = b_ih[lane], bih_z = b_ih[64 + lane], bih_n = b_ih[128 + lane];
  const float bhh_r = b_hh[lane], bhh_z = b_hh[64 + lane], bhh_n = b_hh[128 + lane];
  // prev ∈ {0,1}: gx = prev*w_ih + b_ih == (prev ? w_ih+b_ih : b_ih) bit-exactly.
  const float sum_r = __fadd_rn(w_ih[lane], bih_r);
  const float sum_z = __fadd_rn(w_ih[64 + lane], bih_z);
  const float sum_n = __fadd_rn(w_ih[128 + lane], bih_n);
  const float hwv = head_w[lane];
  const f32x2 hw2 = {hwv, hwv};
  const float hb = head_b[0];
  __syncthreads();  // weights ready; waves independent afterwards

  const float* upA[4];
  const float* upB[4];
#pragma unroll
  for (int p = 0; p < 4; ++p) {
    upA[p] = u + (size_t)(rowBase + 2 * p) * NS;
    upB[p] = u + (size_t)(rowBase + 2 * p + 1) * NS;
  }

  f32x2 h2s[4];
  int prevA[4], prevB[4];
#pragma unroll
  for (int p = 0; p < 4; ++p) {
    h2s[p] = f32x2{0.0f, 0.0f};
    prevA[p] = 0;
    prevB[p] = 0;
    hp[wv][p][lane] = h2s[p];
  }

#pragma unroll 1
  for (int c = 0; c < 16; ++c) {
    float ucA[4], ucB[4];
    int mbA[4], mbB[4];
#pragma unroll
    for (int p = 0; p < 4; ++p) {
      ucA[p] = upA[p][c * 64 + lane];
      ucB[p] = upB[p][c * 64 + lane];
      mbA[p] = 0;
      mbB[p] = 0;
    }
#pragma unroll 1
    for (int tt = 0; tt < 64; ++tt) {
#pragma unroll
      for (int p = 0; p < 4; ++p) {
        const f32x4* hp4 = (const f32x4*)&hp[wv][p][0];
        // gh = h @ w_hh.T, packed over the pair: sequential-k FMA from 0
        // (Eigen gebp clone; components independent).
        f32x2 ar2 = {0.0f, 0.0f}, az2 = {0.0f, 0.0f}, an2 = {0.0f, 0.0f};
#pragma unroll
        for (int kk = 0; kk < 32; ++kk) {
          f32x4 h4 = hp4[kk];          // uniform b128: pairs for k=2kk, 2kk+1
          f32x4 w4 = wzn[kk][lane];    // lane-contiguous b128 (shared by all pairs)
          f32x2 h2a = __builtin_shufflevector(h4, h4, 0, 1);
          f32x2 h2b = __builtin_shufflevector(h4, h4, 2, 3);
          f32x2 wa = __builtin_shufflevector(w4, w4, 0, 1);  // (wz,wn) @ 2kk
          f32x2 wb = __builtin_shufflevector(w4, w4, 2, 3);  // (wz,wn) @ 2kk+1
          PKFMA_LO(ar2, h2a, wr2[kk]);
          PKFMA_LO(az2, h2a, wa);
          PKFMA_HI(an2, h2a, wa);
          PKFMA_HI(ar2, h2b, wr2[kk]);
          PKFMA_LO(az2, h2b, wb);
          PKFMA_HI(an2, h2b, wb);
        }
        // gates, exact reference association (packed mul/add are unfused)
        f32x2 ghr2 = ar2 + bhh_r;
        f32x2 ghz2 = az2 + bhh_z;
        f32x2 ghn2 = an2 + bhh_n;
        f32x2 gxr2 = {prevA[p] ? sum_r : bih_r, prevB[p] ? sum_r : bih_r};
        f32x2 gxz2 = {prevA[p] ? sum_z : bih_z, prevB[p] ? sum_z : bih_z};
        f32x2 gxn2 = {prevA[p] ? sum_n : bih_n, prevB[p] ? sum_n : bih_n};
        f32x2 r2 = xsigmoid2(gxr2 + ghr2);
        f32x2 z2 = xsigmoid2(gxz2 + ghz2);
        f32x2 n2 = xtanh2(gxn2 + r2 * ghn2);
        f32x2 omz = 1.0f - z2;
        f32x2 h2 = omz * n2 + z2 * h2s[p];
        h2s[p] = h2;
        hp[wv][p][lane] = h2;  // for next step's matvec (same-wave, no barrier)

        // head gemv clone: width-16 chunks (shfl, proven) then halving tree
        // tail on DPP row_shl (VALU pipe; lane-0 association preserved).
        f32x2 P2 = h2 * hw2;
        f32x2 t16, t32, t48;
        t16.x = __shfl(P2.x, lane + 16); t16.y = __shfl(P2.y, lane + 16);
        t32.x = __shfl(P2.x, lane + 32); t32.y = __shfl(P2.y, lane + 32);
        t48.x = __shfl(P2.x, lane + 48); t48.y = __shfl(P2.y, lane + 48);
        f32x2 s2 = P2 + t16;
        s2 = s2 + t32;
        s2 = s2 + t48;
        s2.x = dpp_shl_add(s2.x, 0x108); s2.y = dpp_shl_add(s2.y, 0x108);
        s2.x = dpp_shl_add(s2.x, 0x104); s2.y = dpp_shl_add(s2.y, 0x104);
        s2.x = dpp_shl_add(s2.x, 0x102); s2.y = dpp_shl_add(s2.y, 0x102);
        s2.x = dpp_shl_add(s2.x, 0x101); s2.y = dpp_shl_add(s2.y, 0x101);
        float logitA = __fadd_rn(rdlane(s2.x, 0), hb);
        float logitB = __fadd_rn(rdlane(s2.y, 0), hb);
        f32x2 p2 = xsigmoid2(f32x2{logitA, logitB});

        float uAt = rdlane(ucA[p], tt);
        float uBt = rdlane(ucB[p], tt);
        int bA = (uAt < p2.x) ? 1 : 0;
        int bB = (uBt < p2.y) ? 1 : 0;
        prevA[p] = bA;
        prevB[p] = bB;
        mbA[p] = (lane == tt) ? bA : mbA[p];
        mbB[p] = (lane == tt) ? bB : mbB[p];
      }
    }
#pragma unroll
    for (int p = 0; p < 4; ++p) {
      out[(size_t)(rowBase + 2 * p) * NS + c * 64 + lane] = mbA[p];
      out[(size_t)(rowBase + 2 * p + 1) * NS + c * 64 + lane] = mbB[p];
    }
  }
}

extern "C" void kernel_launch(void* const* d_in, const int* in_sizes, int n_in,
                              void* d_out, int out_size, void* d_ws, size_t ws_size,
                              hipStream_t stream) {
  const float* u = (const float*)d_in[0];
  const float* w_ih = (const float*)d_in[1];
  const float* w_hh = (const float*)d_in[2];
  const float* b_ih = (const float*)d_in[3];
  const float* b_hh = (const float*)d_in[4];
  const float* head_w = (const float*)d_in[5];
  const float* head_b = (const float*)d_in[6];
  int* out = (int*)d_out;
  dim3 grid(NB / 32), block(256);
  gru_sample_kernel<<<grid, block, 0, stream>>>(u, w_ih, w_hh, b_ih, b_hh,
                                                head_w, head_b, out);
}